// Round 2
// baseline (364.323 us; speedup 1.0000x reference)
//
#include <hip/hip_runtime.h>
#include <cstddef>

#define BT    8192
#define HD    2048
#define NS    32
#define RDIM  16
#define AD    32
#define CAPP  64             // per-pair-bucket capacity; E[count]=16.5, sigma=4.06 -> 64 is +11.7 sigma
#define NPAIR (NS * NS)      // 1024 buckets, only lo<hi (496) ever used

// ---------------- workspace layout ----------------
// [0, 4096)                          int   cnt[NPAIR]
// [4096, +NPAIR*CAPP*4)              int   tok_list[NPAIR][CAPP]
// next NPAIR*CAPP*4                  float cfa_list[NPAIR][CAPP]   (coef for lo schema)
// next NPAIR*CAPP*4                  float cfb_list[NPAIR][CAPP]   (coef for hi schema)
// next 4 MB                          float UT[32][16][2048]        (U transposed)

__device__ __forceinline__ float dot4(const float4 a, const float4 b) {
    return a.x * b.x + a.y * b.y + a.z * b.z + a.w * b.w;
}
__device__ __forceinline__ void fma4(float4& o, const float a, const float4 b) {
    o.x += a * b.x; o.y += a * b.y; o.z += a * b.z; o.w += a * b.w;
}

// ---------------- prep: zero counters + transpose U -> UT[s][k][j] ----------------
__global__ __launch_bounds__(256) void k_prep(const float* __restrict__ U,
                                              int* __restrict__ cnt,
                                              float* __restrict__ UT) {
    const int bx = blockIdx.x;
    if (bx == NS * 8) {
        for (int i = threadIdx.x; i < NPAIR; i += 256) cnt[i] = 0;
        return;
    }
    const int s = bx >> 3, jc = bx & 7;
    const int j = jc * 256 + threadIdx.x;
    const float4* Up = (const float4*)(U + ((size_t)s * HD + j) * RDIM);
    const float4 a = Up[0], b = Up[1], c = Up[2], d = Up[3];
    float* Tp = UT + (size_t)s * RDIM * HD + j;
    Tp[0]       = a.x; Tp[HD]      = a.y; Tp[2*HD]   = a.z; Tp[3*HD]   = a.w;
    Tp[4*HD]    = b.x; Tp[5*HD]    = b.y; Tp[6*HD]   = b.z; Tp[7*HD]   = b.w;
    Tp[8*HD]    = c.x; Tp[9*HD]    = c.y; Tp[10*HD]  = c.z; Tp[11*HD]  = c.w;
    Tp[12*HD]   = d.x; Tp[13*HD]   = d.y; Tp[14*HD]  = d.z; Tp[15*HD]  = d.w;
}

// ---------------- router ----------------
// 2048 blocks x 4 tokens; wave w covers schemas w*8..w*8+7 in ONE pass (h read once).
// K split across 64 lanes (float4); h register-double-buffered; Wr lane-coalesced
// (L2-resident). ~90 VGPR -> deep occupancy; butterfly reduce; scalar tail
// bucketizes each token into its unordered (lo,hi) schema-pair list.
__global__ __launch_bounds__(256) void k_router(
    const float* __restrict__ h, const float* __restrict__ Wr,
    const float* __restrict__ attr, const float* __restrict__ Wa,
    int* __restrict__ cnt, int* __restrict__ tok_list,
    float* __restrict__ cfa_list, float* __restrict__ cfb_list)
{
    __shared__ float sc_s[4][NS + 1];
    const int tid = threadIdx.x, w = tid >> 6, lane = tid & 63;
    const int t0 = blockIdx.x * 4;
    const int sb = w * 8;

    float vals[32];
    #pragma unroll
    for (int m = 0; m < 32; ++m) vals[m] = 0.f;

    float4 hA[4], hB[4];
    #pragma unroll
    for (int t = 0; t < 4; ++t)
        hA[t] = *(const float4*)(h + (size_t)(t0 + t) * HD + lane * 4);

    #pragma unroll 1
    for (int c = 0; c < 8; c += 2) {
        #pragma unroll
        for (int t = 0; t < 4; ++t)
            hB[t] = *(const float4*)(h + (size_t)(t0 + t) * HD + (c + 1) * 256 + lane * 4);
        #pragma unroll
        for (int sl = 0; sl < 8; ++sl) {
            const float4 wv = *(const float4*)(Wr + (size_t)(sb + sl) * HD + c * 256 + lane * 4);
            #pragma unroll
            for (int t = 0; t < 4; ++t) vals[t * 8 + sl] += dot4(hA[t], wv);
        }
        if (c < 6) {
            #pragma unroll
            for (int t = 0; t < 4; ++t)
                hA[t] = *(const float4*)(h + (size_t)(t0 + t) * HD + (c + 2) * 256 + lane * 4);
        }
        #pragma unroll
        for (int sl = 0; sl < 8; ++sl) {
            const float4 wv = *(const float4*)(Wr + (size_t)(sb + sl) * HD + (c + 1) * 256 + lane * 4);
            #pragma unroll
            for (int t = 0; t < 4; ++t) vals[t * 8 + sl] += dot4(hB[t], wv);
        }
    }

    // reduce 32 values across 64 lanes (pair-adjacent butterfly): lane L (<32)
    // ends holding full sum of value m = L, where m = t*8 + sl.
    #pragma unroll
    for (int st = 0; st < 5; ++st) {
        const int d = 1 << st;
        const bool up = (lane & d) != 0;
        const int half = 16 >> st;
        #pragma unroll
        for (int i = 0; i < half; ++i) {
            const float lo = vals[2 * i], hi = vals[2 * i + 1];
            const float keep = up ? hi : lo, send = up ? lo : hi;
            vals[i] = keep + __shfl_xor(send, d, 64);
        }
    }
    vals[0] += __shfl_xor(vals[0], 32, 64);
    if (lane < 32)
        sc_s[lane >> 3][sb + (lane & 7)] = vals[0];
    __syncthreads();

    if (tid < 4) {
        const int t = tid;
        float m1 = -1e30f, m2 = -1e30f;
        int i1 = 0, i2 = 0;
        #pragma unroll 1
        for (int sI = 0; sI < NS; ++sI) {   // strict > keeps lowest index on ties (lax.top_k)
            const float v = sc_s[t][sI];
            if (v > m1) { m2 = m1; i2 = i1; m1 = v; i1 = sI; }
            else if (v > m2) { m2 = v; i2 = sI; }
        }
        float Z = 0.f;
        #pragma unroll 1
        for (int sI = 0; sI < NS; ++sI) Z += __expf(sc_s[t][sI] - m1);
        const float e2  = __expf(m2 - m1);
        // g = softmax(sc)*mask renormed by (sum + 1e-8): G_i = e_i / (e1+e2 + 1e-8*Z)
        const float den = 1.f + e2 + 1e-8f * Z;
        const float G1 = 1.f / den, G2 = e2 / den;
        float d1 = 0.f, d2 = 0.f;
        #pragma unroll 1
        for (int d = 0; d < AD; ++d) {
            d1 += attr[i1 * AD + d] * Wa[d];
            d2 += attr[i2 * AD + d] * Wa[d];
        }
        const float aw1 = 1.f / (1.f + __expf(-d1));
        const float aw2 = 1.f / (1.f + __expf(-d2));
        const float mult = 0.9f + 0.2f * (G1 * aw1 + G2 * aw2);
        const float c1 = G1 * mult, c2 = G2 * mult;
        const int gt = t0 + t;
        // bucket by unordered pair; keep coefficient attached to its schema
        int lo, hi; float clo, chi;
        if (i1 < i2) { lo = i1; hi = i2; clo = c1; chi = c2; }
        else         { lo = i2; hi = i1; clo = c2; chi = c1; }
        const int p = lo * NS + hi;
        const int pos = atomicAdd(cnt + p, 1);
        if (pos < CAPP) {
            tok_list[p * CAPP + pos] = gt;
            cfa_list[p * CAPP + pos] = clo;
            cfb_list[p * CAPP + pos] = chi;
        }
    }
}

// ---------------- fused pass: per pair-bucket p=(sa,sb), chunk of 8 tokens ----------------
// 2 tokens per wave. Single A-phase computes BOTH schemas' y (h read ONCE):
// vals[64] = {tok r (bit5), schema s (bit4), k (bits0-3)}. Butterfly reduce ->
// lane L holds y for m=L; scale by cf; park in wave-private LDS (no barriers).
// B-phase: out[tok] = ya@V[sa] + yb@V[sb], written exactly once (no RMW, no race).
__global__ __launch_bounds__(256) void k_AB(
    const float* __restrict__ h, const int* __restrict__ cnt,
    const int* __restrict__ tok_list, const float* __restrict__ cfa_list,
    const float* __restrict__ cfb_list, const float* __restrict__ UT,
    const float* __restrict__ V, float* __restrict__ out)
{
    __shared__ __align__(16) float ylds[256];
    const int p = blockIdx.x;
    int count = cnt[p];
    if (count <= 0) return;                  // unused pair (incl. sa>=sb)
    if (count > CAPP) count = CAPP;
    const int sa = p >> 5, sb = p & (NS - 1);
    const int tid = threadIdx.x, w = tid >> 6, lane = tid & 63;
    const float* UTa = UT + (size_t)sa * RDIM * HD;
    const float* UTb = UT + (size_t)sb * RDIM * HD;
    const float* Va  = V  + (size_t)sa * RDIM * HD;
    const float* Vb  = V  + (size_t)sb * RDIM * HD;

    #pragma unroll 1
    for (int ci = blockIdx.y; ci * 8 < count; ci += gridDim.y) {
        int tok[2]; float cfa[2], cfb[2]; bool act[2];
        #pragma unroll
        for (int r = 0; r < 2; ++r) {
            const int idx = ci * 8 + w * 2 + r;
            act[r] = idx < count;
            tok[r] = act[r] ? tok_list[p * CAPP + idx] : 0;
            cfa[r] = act[r] ? cfa_list[p * CAPP + idx] : 0.f;
            cfb[r] = act[r] ? cfb_list[p * CAPP + idx] : 0.f;
        }

        // ---- A-phase (both schemas, one h pass) ----
        float vals[64];
        #pragma unroll
        for (int m = 0; m < 64; ++m) vals[m] = 0.f;

        float4 hA[2], hB[2];
        hA[0] = *(const float4*)(h + (size_t)tok[0] * HD + lane * 4);
        hA[1] = *(const float4*)(h + (size_t)tok[1] * HD + lane * 4);

        #pragma unroll 1
        for (int c = 0; c < 8; c += 2) {
            hB[0] = *(const float4*)(h + (size_t)tok[0] * HD + (c + 1) * 256 + lane * 4);
            hB[1] = *(const float4*)(h + (size_t)tok[1] * HD + (c + 1) * 256 + lane * 4);
            #pragma unroll
            for (int kq = 0; kq < 16; ++kq) {
                const float4 ua = *(const float4*)(UTa + (size_t)kq * HD + c * 256 + lane * 4);
                vals[kq]      += dot4(hA[0], ua);
                vals[32 + kq] += dot4(hA[1], ua);
            }
            #pragma unroll
            for (int kq = 0; kq < 16; ++kq) {
                const float4 ub = *(const float4*)(UTb + (size_t)kq * HD + c * 256 + lane * 4);
                vals[16 + kq] += dot4(hA[0], ub);
                vals[48 + kq] += dot4(hA[1], ub);
            }
            if (c < 6) {
                hA[0] = *(const float4*)(h + (size_t)tok[0] * HD + (c + 2) * 256 + lane * 4);
                hA[1] = *(const float4*)(h + (size_t)tok[1] * HD + (c + 2) * 256 + lane * 4);
            }
            #pragma unroll
            for (int kq = 0; kq < 16; ++kq) {
                const float4 ua = *(const float4*)(UTa + (size_t)kq * HD + (c + 1) * 256 + lane * 4);
                vals[kq]      += dot4(hB[0], ua);
                vals[32 + kq] += dot4(hB[1], ua);
            }
            #pragma unroll
            for (int kq = 0; kq < 16; ++kq) {
                const float4 ub = *(const float4*)(UTb + (size_t)kq * HD + (c + 1) * 256 + lane * 4);
                vals[16 + kq] += dot4(hB[0], ub);
                vals[48 + kq] += dot4(hB[1], ub);
            }
        }

        // reduce 64 values across 64 lanes (pair-adjacent butterfly): lane L ends
        // holding full sum of value m = L  (r = L>>5, s = (L>>4)&1, k = L&15).
        #pragma unroll
        for (int st = 0; st < 6; ++st) {
            const int d = 1 << st;
            const bool up = (lane & d) != 0;
            const int half = 32 >> st;
            #pragma unroll
            for (int i = 0; i < half; ++i) {
                const float lo = vals[2 * i], hi = vals[2 * i + 1];
                const float keep = up ? hi : lo, send = up ? lo : hi;
                vals[i] = keep + __shfl_xor(send, d, 64);
            }
        }
        {
            const int rr = lane >> 5, ss = (lane >> 4) & 1;
            const float ca = rr ? cfa[1] : cfa[0];
            const float cb = rr ? cfb[1] : cfb[0];
            ylds[w * 64 + lane] = vals[0] * (ss ? cb : ca);
        }
        // wave-private LDS region: written and read only by wave w -> barrier-free

        // ---- B-phase ----
        #pragma unroll 1
        for (int c = 0; c < 8; ++c) {
            float4 o0 = make_float4(0.f, 0.f, 0.f, 0.f);
            float4 o1 = make_float4(0.f, 0.f, 0.f, 0.f);

            #pragma unroll
            for (int kg = 0; kg < 4; ++kg) {
                float4 vv[4];
                #pragma unroll
                for (int q = 0; q < 4; ++q)
                    vv[q] = *(const float4*)(Va + (size_t)(kg * 4 + q) * HD + c * 256 + lane * 4);
                const float4 y0 = *(const float4*)&ylds[w * 64 +  0 + kg * 4];
                const float4 y1 = *(const float4*)&ylds[w * 64 + 32 + kg * 4];
                fma4(o0, y0.x, vv[0]); fma4(o0, y0.y, vv[1]); fma4(o0, y0.z, vv[2]); fma4(o0, y0.w, vv[3]);
                fma4(o1, y1.x, vv[0]); fma4(o1, y1.y, vv[1]); fma4(o1, y1.z, vv[2]); fma4(o1, y1.w, vv[3]);
            }
            #pragma unroll
            for (int kg = 0; kg < 4; ++kg) {
                float4 vv[4];
                #pragma unroll
                for (int q = 0; q < 4; ++q)
                    vv[q] = *(const float4*)(Vb + (size_t)(kg * 4 + q) * HD + c * 256 + lane * 4);
                const float4 y0 = *(const float4*)&ylds[w * 64 + 16 + kg * 4];
                const float4 y1 = *(const float4*)&ylds[w * 64 + 48 + kg * 4];
                fma4(o0, y0.x, vv[0]); fma4(o0, y0.y, vv[1]); fma4(o0, y0.z, vv[2]); fma4(o0, y0.w, vv[3]);
                fma4(o1, y1.x, vv[0]); fma4(o1, y1.y, vv[1]); fma4(o1, y1.z, vv[2]); fma4(o1, y1.w, vv[3]);
            }
            if (act[0]) *(float4*)(out + (size_t)tok[0] * HD + c * 256 + lane * 4) = o0;
            if (act[1]) *(float4*)(out + (size_t)tok[1] * HD + c * 256 + lane * 4) = o1;
        }
    }
}

extern "C" void kernel_launch(void* const* d_in, const int* in_sizes, int n_in,
                              void* d_out, int out_size, void* d_ws, size_t ws_size,
                              hipStream_t stream)
{
    const float* h    = (const float*)d_in[0];
    const float* Wr   = (const float*)d_in[1];
    const float* U    = (const float*)d_in[2];
    const float* V    = (const float*)d_in[3];
    const float* attr = (const float*)d_in[4];
    const float* Wa   = (const float*)d_in[5];
    float* outp = (float*)d_out;

    char* ws = (char*)d_ws;
    int*   cnt      = (int*)ws;
    int*   tok_list = (int*)(ws + 4096);
    float* cfa_list = (float*)(ws + 4096 + (size_t)NPAIR * CAPP * 4);
    float* cfb_list = (float*)(ws + 4096 + (size_t)2 * NPAIR * CAPP * 4);
    float* UT       = (float*)(ws + 4096 + (size_t)3 * NPAIR * CAPP * 4);

    hipLaunchKernelGGL(k_prep,   dim3(NS * 8 + 1), dim3(256), 0, stream, U, cnt, UT);
    hipLaunchKernelGGL(k_router, dim3(BT / 4),     dim3(256), 0, stream,
                       h, Wr, attr, Wa, cnt, tok_list, cfa_list, cfb_list);
    hipLaunchKernelGGL(k_AB,     dim3(NPAIR, 8),   dim3(256), 0, stream,
                       h, cnt, tok_list, cfa_list, cfb_list, UT, V, outp);
}

// Round 3
// 354.604 us; speedup vs baseline: 1.0274x; 1.0274x over previous
//
#include <hip/hip_runtime.h>
#include <cstddef>

#define BT    8192
#define HD    2048
#define NS    32
#define RDIM  16
#define AD    32
#define CAPP  64             // per-pair-bucket capacity; E[count]=16.5, sigma~4 -> 64 is +11 sigma
#define NPAIR (NS * NS)      // 1024 buckets, only lo<hi (496) ever used

// ---------------- workspace layout ----------------
// [0, 4096)                          int   cnt[NPAIR]
// [4096, +NPAIR*CAPP*4)              int   tok_list[NPAIR][CAPP]
// next NPAIR*CAPP*4                  float cfa_list[NPAIR][CAPP]   (coef for lo schema)
// next NPAIR*CAPP*4                  float cfb_list[NPAIR][CAPP]   (coef for hi schema)
// next 4 MB                          float UT[32][16][2048]        (U transposed)
// next 1 MB                          float sc_g[8192][32]          (router scores)
// next 128 B                         float aw[32]                  (sigmoid(attr@Wa))

__device__ __forceinline__ float dot4(const float4 a, const float4 b) {
    return a.x * b.x + a.y * b.y + a.z * b.z + a.w * b.w;
}
__device__ __forceinline__ void fma4(float4& o, const float a, const float4 b) {
    o.x += a * b.x; o.y += a * b.y; o.z += a * b.z; o.w += a * b.w;
}

// ---------------- prep: zero counters + transpose U + aw = sigmoid(attr@Wa) ----------------
__global__ __launch_bounds__(256) void k_prep(const float* __restrict__ U,
                                              const float* __restrict__ attr,
                                              const float* __restrict__ Wa,
                                              int* __restrict__ cnt,
                                              float* __restrict__ UT,
                                              float* __restrict__ aw) {
    const int bx = blockIdx.x;
    if (bx == NS * 8) {
        for (int i = threadIdx.x; i < NPAIR; i += 256) cnt[i] = 0;
        if (threadIdx.x < NS) {
            float s = 0.f;
            #pragma unroll 1
            for (int d = 0; d < AD; ++d) s += attr[threadIdx.x * AD + d] * Wa[d];
            aw[threadIdx.x] = 1.f / (1.f + __expf(-s));
        }
        return;
    }
    const int s = bx >> 3, jc = bx & 7;
    const int j = jc * 256 + threadIdx.x;
    const float4* Up = (const float4*)(U + ((size_t)s * HD + j) * RDIM);
    const float4 a = Up[0], b = Up[1], c = Up[2], d = Up[3];
    float* Tp = UT + (size_t)s * RDIM * HD + j;
    Tp[0]       = a.x; Tp[HD]      = a.y; Tp[2*HD]   = a.z; Tp[3*HD]   = a.w;
    Tp[4*HD]    = b.x; Tp[5*HD]    = b.y; Tp[6*HD]   = b.z; Tp[7*HD]   = b.w;
    Tp[8*HD]    = c.x; Tp[9*HD]    = c.y; Tp[10*HD]  = c.z; Tp[11*HD]  = c.w;
    Tp[12*HD]   = d.x; Tp[13*HD]   = d.y; Tp[14*HD]  = d.z; Tp[15*HD]  = d.w;
}

// ---------------- router: pure score GEMV ----------------
// 2048 blocks x 4 tokens; wave w covers schemas w*8..w*8+7 in one pass (h read once).
// K split across 64 lanes (float4); h register-double-buffered; Wr lane-coalesced
// (L2-resident). Butterfly reduce -> lane L (<32) holds score (t=L>>3, sl=L&7);
// write raw scores and RETIRE. No LDS, no barrier, no serial tail (moved to k_tail).
__global__ __launch_bounds__(256) void k_router(
    const float* __restrict__ h, const float* __restrict__ Wr,
    float* __restrict__ sc_g)
{
    const int tid = threadIdx.x, w = tid >> 6, lane = tid & 63;
    const int t0 = blockIdx.x * 4;
    const int sb = w * 8;

    float vals[32];
    #pragma unroll
    for (int m = 0; m < 32; ++m) vals[m] = 0.f;

    float4 hA[4], hB[4];
    #pragma unroll
    for (int t = 0; t < 4; ++t)
        hA[t] = *(const float4*)(h + (size_t)(t0 + t) * HD + lane * 4);

    #pragma unroll 1
    for (int c = 0; c < 8; c += 2) {
        #pragma unroll
        for (int t = 0; t < 4; ++t)
            hB[t] = *(const float4*)(h + (size_t)(t0 + t) * HD + (c + 1) * 256 + lane * 4);
        #pragma unroll
        for (int sl = 0; sl < 8; ++sl) {
            const float4 wv = *(const float4*)(Wr + (size_t)(sb + sl) * HD + c * 256 + lane * 4);
            #pragma unroll
            for (int t = 0; t < 4; ++t) vals[t * 8 + sl] += dot4(hA[t], wv);
        }
        if (c < 6) {
            #pragma unroll
            for (int t = 0; t < 4; ++t)
                hA[t] = *(const float4*)(h + (size_t)(t0 + t) * HD + (c + 2) * 256 + lane * 4);
        }
        #pragma unroll
        for (int sl = 0; sl < 8; ++sl) {
            const float4 wv = *(const float4*)(Wr + (size_t)(sb + sl) * HD + (c + 1) * 256 + lane * 4);
            #pragma unroll
            for (int t = 0; t < 4; ++t) vals[t * 8 + sl] += dot4(hB[t], wv);
        }
    }

    // reduce 32 values across 64 lanes (pair-adjacent butterfly): lane L (<32)
    // ends holding full sum of value m = L, where m = t*8 + sl.
    #pragma unroll
    for (int st = 0; st < 5; ++st) {
        const int d = 1 << st;
        const bool up = (lane & d) != 0;
        const int half = 16 >> st;
        #pragma unroll
        for (int i = 0; i < half; ++i) {
            const float lo = vals[2 * i], hi = vals[2 * i + 1];
            const float keep = up ? hi : lo, send = up ? lo : hi;
            vals[i] = keep + __shfl_xor(send, d, 64);
        }
    }
    vals[0] += __shfl_xor(vals[0], 32, 64);
    if (lane < 32)
        sc_g[(size_t)(t0 + (lane >> 3)) * NS + sb + (lane & 7)] = vals[0];
}

// ---------------- tail: thread-per-token top-2 / softmax / bucketize ----------------
// 8192 threads (32 blocks). Fully unrolled so s[32] stays in registers (rule #20).
__global__ __launch_bounds__(256) void k_tail(
    const float* __restrict__ sc_g, const float* __restrict__ aw,
    int* __restrict__ cnt, int* __restrict__ tok_list,
    float* __restrict__ cfa_list, float* __restrict__ cfb_list)
{
    const int t = blockIdx.x * 256 + threadIdx.x;
    float s[32];
    const float4* sp = (const float4*)(sc_g + (size_t)t * NS);
    #pragma unroll
    for (int j = 0; j < 8; ++j) {
        const float4 v = sp[j];
        s[4*j] = v.x; s[4*j+1] = v.y; s[4*j+2] = v.z; s[4*j+3] = v.w;
    }
    float m1 = -1e30f, m2 = -1e30f;
    int i1 = 0, i2 = 0;
    #pragma unroll
    for (int k = 0; k < 32; ++k) {   // strict > keeps lowest index on ties (lax.top_k)
        const float v = s[k];
        if (v > m1) { m2 = m1; i2 = i1; m1 = v; i1 = k; }
        else if (v > m2) { m2 = v; i2 = k; }
    }
    float Z = 0.f;
    #pragma unroll
    for (int k = 0; k < 32; ++k) Z += __expf(s[k] - m1);
    const float e2  = __expf(m2 - m1);
    // g = softmax(sc)*mask renormed by (sum + 1e-8): G_i = e_i / (e1+e2 + 1e-8*Z)
    const float den = 1.f + e2 + 1e-8f * Z;
    const float G1 = 1.f / den, G2 = e2 / den;
    const float aw1 = aw[i1], aw2 = aw[i2];
    const float mult = 0.9f + 0.2f * (G1 * aw1 + G2 * aw2);
    const float c1 = G1 * mult, c2 = G2 * mult;
    // bucket by unordered pair; keep coefficient attached to its schema
    int lo, hi; float clo, chi;
    if (i1 < i2) { lo = i1; hi = i2; clo = c1; chi = c2; }
    else         { lo = i2; hi = i1; clo = c2; chi = c1; }
    const int p = lo * NS + hi;
    const int pos = atomicAdd(cnt + p, 1);
    if (pos < CAPP) {
        tok_list[p * CAPP + pos] = t;
        cfa_list[p * CAPP + pos] = clo;
        cfb_list[p * CAPP + pos] = chi;
    }
}

// ---------------- fused pass: pair-bucket p=(sa,sb), one 8-token chunk per block ----------------
// Key change vs r2: UT/V operand slices are LDS-STAGED per c-block (2x16KB, coalesced
// burst shared by all 4 waves) instead of each wave privately streaming 512 float4s
// from L2 (~300cy latency, ~8 outstanding -> 22us/wave). Compute reads LDS (~6-12cy).
// 2 tok/wave, single A-pass for BOTH schemas (h read once); out written exactly once.
__global__ __launch_bounds__(256) void k_AB(
    const float* __restrict__ h, const int* __restrict__ cnt,
    const int* __restrict__ tok_list, const float* __restrict__ cfa_list,
    const float* __restrict__ cfb_list, const float* __restrict__ UT,
    const float* __restrict__ V, float* __restrict__ out)
{
    __shared__ __align__(16) float stg[2][RDIM * 256];   // 2 x 16 KB operand slices
    __shared__ __align__(16) float ylds[256];
    const int p = blockIdx.x;
    int count = cnt[p];
    if (count <= 0) return;                  // unused pair (incl. sa>=sb)
    if (count > CAPP) count = CAPP;
    const int ci = blockIdx.y;               // gridDim.y = 8 >= max chunks -> <=1 chunk/block
    if (ci * 8 >= count) return;
    const int sa = p >> 5, sb = p & (NS - 1);
    const int tid = threadIdx.x, w = tid >> 6, lane = tid & 63;
    const float* UTa = UT + (size_t)sa * RDIM * HD;
    const float* UTb = UT + (size_t)sb * RDIM * HD;
    const float* Va  = V  + (size_t)sa * RDIM * HD;
    const float* Vb  = V  + (size_t)sb * RDIM * HD;
    float4* const stga = (float4*)stg[0];
    float4* const stgb = (float4*)stg[1];

    int tok[2]; float cfa[2], cfb[2]; bool act[2];
    #pragma unroll
    for (int r = 0; r < 2; ++r) {
        const int idx = ci * 8 + w * 2 + r;
        act[r] = idx < count;
        tok[r] = act[r] ? tok_list[p * CAPP + idx] : 0;
        cfa[r] = act[r] ? cfa_list[p * CAPP + idx] : 0.f;
        cfb[r] = act[r] ? cfb_list[p * CAPP + idx] : 0.f;
    }

    // ---- A-phase: vals[64] = {tok r (bit5), schema s (bit4), k (bits0-3)} ----
    float vals[64];
    #pragma unroll
    for (int m = 0; m < 64; ++m) vals[m] = 0.f;

    #pragma unroll 1
    for (int c = 0; c < 8; ++c) {
        // stage UTa/UTb slice c: 1024 float4 each, 4 per thread, coalesced
        #pragma unroll
        for (int j = 0; j < 4; ++j) {
            const int f = tid + j * 256;
            const int k = f >> 6, e = f & 63;
            stga[f] = *((const float4*)(UTa + (size_t)k * HD + c * 256) + e);
            stgb[f] = *((const float4*)(UTb + (size_t)k * HD + c * 256) + e);
        }
        const float4 h0 = *(const float4*)(h + (size_t)tok[0] * HD + c * 256 + lane * 4);
        const float4 h1 = *(const float4*)(h + (size_t)tok[1] * HD + c * 256 + lane * 4);
        __syncthreads();
        #pragma unroll
        for (int kq = 0; kq < 16; ++kq) {
            const float4 ua = stga[kq * 64 + lane];
            vals[kq]      += dot4(h0, ua);
            vals[32 + kq] += dot4(h1, ua);
        }
        #pragma unroll
        for (int kq = 0; kq < 16; ++kq) {
            const float4 ub = stgb[kq * 64 + lane];
            vals[16 + kq] += dot4(h0, ub);
            vals[48 + kq] += dot4(h1, ub);
        }
        __syncthreads();   // protect stg before next iteration's staging writes
    }

    // butterfly reduce 64 values across 64 lanes: lane L ends holding value m=L
    // (r = L>>5, s = (L>>4)&1, k = L&15).
    #pragma unroll
    for (int st = 0; st < 6; ++st) {
        const int d = 1 << st;
        const bool up = (lane & d) != 0;
        const int half = 32 >> st;
        #pragma unroll
        for (int i = 0; i < half; ++i) {
            const float lo = vals[2 * i], hi = vals[2 * i + 1];
            const float keep = up ? hi : lo, send = up ? lo : hi;
            vals[i] = keep + __shfl_xor(send, d, 64);
        }
    }
    {
        const int rr = lane >> 5, ss = (lane >> 4) & 1;
        const float ca = rr ? cfa[1] : cfa[0];
        const float cb = rr ? cfb[1] : cfb[0];
        ylds[w * 64 + lane] = vals[0] * (ss ? cb : ca);   // wave-private region
    }

    // ---- B-phase: out[tok] = ya@V[sa] + yb@V[sb], V slices LDS-staged ----
    #pragma unroll 1
    for (int c = 0; c < 8; ++c) {
        #pragma unroll
        for (int j = 0; j < 4; ++j) {
            const int f = tid + j * 256;
            const int k = f >> 6, e = f & 63;
            stga[f] = *((const float4*)(Va + (size_t)k * HD + c * 256) + e);
            stgb[f] = *((const float4*)(Vb + (size_t)k * HD + c * 256) + e);
        }
        __syncthreads();
        float4 o0 = make_float4(0.f, 0.f, 0.f, 0.f);
        float4 o1 = make_float4(0.f, 0.f, 0.f, 0.f);
        #pragma unroll
        for (int kg = 0; kg < 4; ++kg) {
            float4 vv[4];
            #pragma unroll
            for (int q = 0; q < 4; ++q) vv[q] = stga[(kg * 4 + q) * 64 + lane];
            const float4 y0 = *(const float4*)&ylds[w * 64 +  0 + kg * 4];
            const float4 y1 = *(const float4*)&ylds[w * 64 + 32 + kg * 4];
            fma4(o0, y0.x, vv[0]); fma4(o0, y0.y, vv[1]); fma4(o0, y0.z, vv[2]); fma4(o0, y0.w, vv[3]);
            fma4(o1, y1.x, vv[0]); fma4(o1, y1.y, vv[1]); fma4(o1, y1.z, vv[2]); fma4(o1, y1.w, vv[3]);
        }
        #pragma unroll
        for (int kg = 0; kg < 4; ++kg) {
            float4 vv[4];
            #pragma unroll
            for (int q = 0; q < 4; ++q) vv[q] = stgb[(kg * 4 + q) * 64 + lane];
            const float4 y0 = *(const float4*)&ylds[w * 64 + 16 + kg * 4];
            const float4 y1 = *(const float4*)&ylds[w * 64 + 48 + kg * 4];
            fma4(o0, y0.x, vv[0]); fma4(o0, y0.y, vv[1]); fma4(o0, y0.z, vv[2]); fma4(o0, y0.w, vv[3]);
            fma4(o1, y1.x, vv[0]); fma4(o1, y1.y, vv[1]); fma4(o1, y1.z, vv[2]); fma4(o1, y1.w, vv[3]);
        }
        if (act[0]) *(float4*)(out + (size_t)tok[0] * HD + c * 256 + lane * 4) = o0;
        if (act[1]) *(float4*)(out + (size_t)tok[1] * HD + c * 256 + lane * 4) = o1;
        __syncthreads();   // protect stg before next iteration's staging writes
    }
}

extern "C" void kernel_launch(void* const* d_in, const int* in_sizes, int n_in,
                              void* d_out, int out_size, void* d_ws, size_t ws_size,
                              hipStream_t stream)
{
    const float* h    = (const float*)d_in[0];
    const float* Wr   = (const float*)d_in[1];
    const float* U    = (const float*)d_in[2];
    const float* V    = (const float*)d_in[3];
    const float* attr = (const float*)d_in[4];
    const float* Wa   = (const float*)d_in[5];
    float* outp = (float*)d_out;

    char* ws = (char*)d_ws;
    int*   cnt      = (int*)ws;
    int*   tok_list = (int*)(ws + 4096);
    float* cfa_list = (float*)(ws + 4096 + (size_t)NPAIR * CAPP * 4);
    float* cfb_list = (float*)(ws + 4096 + (size_t)2 * NPAIR * CAPP * 4);
    float* UT       = (float*)(ws + 4096 + (size_t)3 * NPAIR * CAPP * 4);
    float* sc_g     = UT + (size_t)NS * RDIM * HD;
    float* aw       = sc_g + (size_t)BT * NS;

    hipLaunchKernelGGL(k_prep,   dim3(NS * 8 + 1), dim3(256), 0, stream,
                       U, attr, Wa, cnt, UT, aw);
    hipLaunchKernelGGL(k_router, dim3(BT / 4),     dim3(256), 0, stream, h, Wr, sc_g);
    hipLaunchKernelGGL(k_tail,   dim3(BT / 256),   dim3(256), 0, stream,
                       sc_g, aw, cnt, tok_list, cfa_list, cfb_list);
    hipLaunchKernelGGL(k_AB,     dim3(NPAIR, 8),   dim3(256), 0, stream,
                       h, cnt, tok_list, cfa_list, cfb_list, UT, V, outp);
}

// Round 4
// 299.520 us; speedup vs baseline: 1.2164x; 1.1839x over previous
//
#include <hip/hip_runtime.h>
#include <cstddef>

#define BT    8192
#define HD    2048
#define NS    32
#define RDIM  16
#define AD    32
#define CAPL  448            // per (slot,schema) list cap; lambda=256, sigma=15.7 -> +12 sigma
#define NLIST 64

// ---------------- workspace layout ----------------
// [0, 256)                     int   cnt[64]            (slot*32 + schema)
// [256, +64*CAPL*4)            int   tok_list[64][CAPL]
// next 64*CAPL*4               float cf_list[64][CAPL]
// next 4 MB                    float UT[32][16][2048]   (U transposed)
// next 1 MB                    float sc_g[8192][32]     (router scores)
// next 128 B                   float aw[32]             (sigmoid(attr@Wa))
// next 1.75 MB                 float y_ws[64][CAPL][16]

__device__ __forceinline__ float dot4(const float4 a, const float4 b) {
    return a.x * b.x + a.y * b.y + a.z * b.z + a.w * b.w;
}
__device__ __forceinline__ void fma4(float4& o, const float a, const float4 b) {
    o.x += a * b.x; o.y += a * b.y; o.z += a * b.z; o.w += a * b.w;
}

// ---------------- prep: zero counters + transpose U + aw = sigmoid(attr@Wa) ----------------
__global__ __launch_bounds__(256) void k_prep(const float* __restrict__ U,
                                              const float* __restrict__ attr,
                                              const float* __restrict__ Wa,
                                              int* __restrict__ cnt,
                                              float* __restrict__ UT,
                                              float* __restrict__ aw) {
    const int bx = blockIdx.x;
    if (bx == NS * 8) {
        if (threadIdx.x < NLIST) cnt[threadIdx.x] = 0;
        if (threadIdx.x >= 64 && threadIdx.x < 64 + NS) {
            const int s = threadIdx.x - 64;
            float sum = 0.f;
            #pragma unroll 1
            for (int d = 0; d < AD; ++d) sum += attr[s * AD + d] * Wa[d];
            aw[s] = 1.f / (1.f + __expf(-sum));
        }
        return;
    }
    const int s = bx >> 3, jc = bx & 7;
    const int j = jc * 256 + threadIdx.x;
    const float4* Up = (const float4*)(U + ((size_t)s * HD + j) * RDIM);
    const float4 a = Up[0], b = Up[1], c = Up[2], d = Up[3];
    float* Tp = UT + (size_t)s * RDIM * HD + j;
    Tp[0]       = a.x; Tp[HD]      = a.y; Tp[2*HD]   = a.z; Tp[3*HD]   = a.w;
    Tp[4*HD]    = b.x; Tp[5*HD]    = b.y; Tp[6*HD]   = b.z; Tp[7*HD]   = b.w;
    Tp[8*HD]    = c.x; Tp[9*HD]    = c.y; Tp[10*HD]  = c.z; Tp[11*HD]  = c.w;
    Tp[12*HD]   = d.x; Tp[13*HD]   = d.y; Tp[14*HD]  = d.z; Tp[15*HD]  = d.w;
}

// ---------------- router: Wr staged in LDS, 16 tokens/block, 8 waves ----------------
// Per c-slice of 256 dims: stage Wr[32 sch][256] (32 KB, coalesced, shared by all
// 8 waves) then each wave computes 2 tokens x 32 schemas from LDS (64 acc/lane,
// lane-K-split). Butterfly reduce -> lane L holds (t=L>>5, s=L&31); write raw
// scores. Top-k tail is a separate thread-per-token kernel.
__global__ __launch_bounds__(512) void k_router(
    const float* __restrict__ h, const float* __restrict__ Wr,
    float* __restrict__ sc_g)
{
    __shared__ __align__(16) float wst[NS * 256];     // 32 KB
    const int tid = threadIdx.x, w = tid >> 6, lane = tid & 63;
    const int t0 = blockIdx.x * 16;
    const int ta = t0 + w * 2, tb = ta + 1;
    float4* const wst4 = (float4*)wst;

    float acc[64];
    #pragma unroll
    for (int m = 0; m < 64; ++m) acc[m] = 0.f;

    #pragma unroll 1
    for (int cq = 0; cq < 8; ++cq) {
        __syncthreads();   // protect wst from previous iteration's readers
        #pragma unroll
        for (int j = 0; j < 4; ++j) {
            const int f = tid + j * 512;
            const int s = f >> 6, e = f & 63;
            wst4[f] = *((const float4*)(Wr + (size_t)s * HD + cq * 256) + e);
        }
        const float4 h0 = *(const float4*)(h + (size_t)ta * HD + cq * 256 + lane * 4);
        const float4 h1 = *(const float4*)(h + (size_t)tb * HD + cq * 256 + lane * 4);
        __syncthreads();
        #pragma unroll
        for (int s = 0; s < 32; ++s) {
            const float4 wv = wst4[s * 64 + lane];
            acc[s]      += dot4(h0, wv);
            acc[32 + s] += dot4(h1, wv);
        }
    }

    // butterfly reduce 64 values across 64 lanes: lane L ends with value m=L
    #pragma unroll
    for (int st = 0; st < 6; ++st) {
        const int d = 1 << st;
        const bool up = (lane & d) != 0;
        const int half = 32 >> st;
        #pragma unroll
        for (int i = 0; i < half; ++i) {
            const float lo = acc[2 * i], hi = acc[2 * i + 1];
            const float keep = up ? hi : lo, send = up ? lo : hi;
            acc[i] = keep + __shfl_xor(send, d, 64);
        }
    }
    sc_g[(size_t)(ta + (lane >> 5)) * NS + (lane & 31)] = acc[0];
}

// ---------------- tail: thread-per-token top-2 / softmax / list build ----------------
__global__ __launch_bounds__(256) void k_tail(
    const float* __restrict__ sc_g, const float* __restrict__ aw,
    int* __restrict__ cnt, int* __restrict__ tok_list, float* __restrict__ cf_list)
{
    const int t = blockIdx.x * 256 + threadIdx.x;
    float s[32];
    const float4* sp = (const float4*)(sc_g + (size_t)t * NS);
    #pragma unroll
    for (int j = 0; j < 8; ++j) {
        const float4 v = sp[j];
        s[4*j] = v.x; s[4*j+1] = v.y; s[4*j+2] = v.z; s[4*j+3] = v.w;
    }
    float m1 = -1e30f, m2 = -1e30f;
    int i1 = 0, i2 = 0;
    #pragma unroll
    for (int k = 0; k < 32; ++k) {   // strict > keeps lowest index on ties (lax.top_k)
        const float v = s[k];
        if (v > m1) { m2 = m1; i2 = i1; m1 = v; i1 = k; }
        else if (v > m2) { m2 = v; i2 = k; }
    }
    float Z = 0.f;
    #pragma unroll
    for (int k = 0; k < 32; ++k) Z += __expf(s[k] - m1);
    const float e2  = __expf(m2 - m1);
    // g = softmax(sc)*mask renormed by (sum + 1e-8): G_i = e_i / (e1+e2 + 1e-8*Z)
    const float den = 1.f + e2 + 1e-8f * Z;
    const float G1 = 1.f / den, G2 = e2 / den;
    const float mult = 0.9f + 0.2f * (G1 * aw[i1] + G2 * aw[i2]);
    const float c1 = G1 * mult, c2 = G2 * mult;
    int p = atomicAdd(cnt + i1, 1);
    if (p < CAPL) { tok_list[i1 * CAPL + p] = t; cf_list[i1 * CAPL + p] = c1; }
    p = atomicAdd(cnt + NS + i2, 1);
    if (p < CAPL) { tok_list[(NS + i2) * CAPL + p] = t; cf_list[(NS + i2) * CAPL + p] = c2; }
}

// ---------------- pass A: y[g][tok][k] = cf * (h[tok,:] @ U[s][:,k]) ----------------
// Block = 32 tokens of list g, 8 waves x 4 tok. UT[s] staged in 32 KB quarters
// ([16 k][512 dims]) shared by all waves; per c-iter each lane: 4 gathered h-loads
// + 16 LDS reads + 64 dot4 into acc[64]. Butterfly -> coalesced 64-float y write.
__global__ __launch_bounds__(512) void k_A(
    const float* __restrict__ h, const int* __restrict__ cnt,
    const int* __restrict__ tok_list, const float* __restrict__ cf_list,
    const float* __restrict__ UT, float* __restrict__ y_ws)
{
    __shared__ __align__(16) float ust[RDIM * 512];   // 32 KB
    const int g = blockIdx.x, s = g & (NS - 1);
    int count = cnt[g]; if (count > CAPL) count = CAPL;
    const int ci = blockIdx.y;
    if (ci * 32 >= count) return;
    const int tid = threadIdx.x, w = tid >> 6, lane = tid & 63;
    const float* UTs = UT + (size_t)s * RDIM * HD;
    float4* const ust4 = (float4*)ust;

    int tok[4]; float cf[4];
    #pragma unroll
    for (int r = 0; r < 4; ++r) {
        const int idx = ci * 32 + w * 4 + r;
        const bool vld = idx < count;
        tok[r] = vld ? tok_list[g * CAPL + idx] : 0;
        cf[r]  = vld ? cf_list[g * CAPL + idx] : 0.f;
    }

    float acc[64];
    #pragma unroll
    for (int m = 0; m < 64; ++m) acc[m] = 0.f;

    #pragma unroll 1
    for (int cq = 0; cq < 4; ++cq) {
        __syncthreads();   // protect ust from previous iteration's readers
        #pragma unroll
        for (int j = 0; j < 4; ++j) {
            const int f = tid + j * 512;
            const int k = f >> 7, e = f & 127;
            ust4[f] = *((const float4*)(UTs + (size_t)k * HD + cq * 512) + e);
        }
        __syncthreads();
        #pragma unroll
        for (int c2 = 0; c2 < 2; ++c2) {
            float4 hv[4];
            #pragma unroll
            for (int r = 0; r < 4; ++r)
                hv[r] = *(const float4*)(h + (size_t)tok[r] * HD + cq * 512 + c2 * 256 + lane * 4);
            #pragma unroll
            for (int k = 0; k < 16; ++k) {
                const float4 uv = ust4[k * 128 + c2 * 64 + lane];
                #pragma unroll
                for (int r = 0; r < 4; ++r)
                    acc[r * 16 + k] += dot4(hv[r], uv);
            }
        }
    }

    // butterfly reduce: lane L ends holding value m=L (r = L>>4, k = L&15)
    #pragma unroll
    for (int st = 0; st < 6; ++st) {
        const int d = 1 << st;
        const bool up = (lane & d) != 0;
        const int half = 32 >> st;
        #pragma unroll
        for (int i = 0; i < half; ++i) {
            const float lo = acc[2 * i], hi = acc[2 * i + 1];
            const float keep = up ? hi : lo, send = up ? lo : hi;
            acc[i] = keep + __shfl_xor(send, d, 64);
        }
    }
    const int rr = lane >> 4;
    const float cfv = rr == 0 ? cf[0] : rr == 1 ? cf[1] : rr == 2 ? cf[2] : cf[3];
    y_ws[((size_t)g * CAPL + ci * 32 + w * 4) * 16 + lane] = acc[0] * cfv;
}

// ---------------- pass B: out[tok][:] (+)= y[g][tok][:] @ V[s] ----------------
// Block = 64 tokens, 8 waves x 8 tok. V[s] staged in 32 KB quarters; y (4 KB) and
// token ids in LDS. slot 0 stores (argmax list covers each token exactly once),
// slot 1 non-atomic RMW add (separate launch -> ordered).
__global__ __launch_bounds__(512) void k_B(
    const float* __restrict__ V, const int* __restrict__ cnt,
    const int* __restrict__ tok_list, const float* __restrict__ y_ws,
    float* __restrict__ out, const int slot)
{
    __shared__ __align__(16) float vst[RDIM * 512];   // 32 KB
    __shared__ __align__(16) float yld[64 * 16];      // 4 KB
    __shared__ int toks_s[64];
    const int sch = blockIdx.x;
    const int g = slot * NS + sch;
    int count = cnt[g]; if (count > CAPL) count = CAPL;
    const int ci = blockIdx.y;
    if (ci * 64 >= count) return;
    const int tid = threadIdx.x, w = tid >> 6, lane = tid & 63;
    const float* Vs = V + (size_t)sch * RDIM * HD;
    float4* const vst4 = (float4*)vst;
    float4* const yld4 = (float4*)yld;

    if (tid < 64)
        toks_s[tid] = (ci * 64 + tid < count) ? tok_list[g * CAPL + ci * 64 + tid] : -1;
    if (tid < 256)
        yld4[tid] = *((const float4*)(y_ws + ((size_t)g * CAPL + ci * 64) * 16) + tid);
    __syncthreads();

    int tok[8]; bool act[8];
    #pragma unroll
    for (int r = 0; r < 8; ++r) {
        const int tv = toks_s[w * 8 + r];
        act[r] = tv >= 0; tok[r] = act[r] ? tv : 0;
    }

    #pragma unroll 1
    for (int cq = 0; cq < 4; ++cq) {
        __syncthreads();   // protect vst from previous iteration's readers
        #pragma unroll
        for (int j = 0; j < 4; ++j) {
            const int f = tid + j * 512;
            const int k = f >> 7, e = f & 127;
            vst4[f] = *((const float4*)(Vs + (size_t)k * HD + cq * 512) + e);
        }
        __syncthreads();
        #pragma unroll
        for (int c2 = 0; c2 < 2; ++c2) {
            const int coff = cq * 512 + c2 * 256 + lane * 4;
            float4 ov[8];
            if (slot) {
                #pragma unroll
                for (int r = 0; r < 8; ++r)
                    if (act[r]) ov[r] = *(const float4*)(out + (size_t)tok[r] * HD + coff);
            }
            float4 o[8];
            #pragma unroll
            for (int r = 0; r < 8; ++r) o[r] = make_float4(0.f, 0.f, 0.f, 0.f);

            #pragma unroll
            for (int kg = 0; kg < 4; ++kg) {
                float4 vv[4];
                #pragma unroll
                for (int q = 0; q < 4; ++q)
                    vv[q] = vst4[(kg * 4 + q) * 128 + c2 * 64 + lane];
                #pragma unroll
                for (int r = 0; r < 8; ++r) {
                    const float4 yv = yld4[(w * 8 + r) * 4 + kg];
                    fma4(o[r], yv.x, vv[0]); fma4(o[r], yv.y, vv[1]);
                    fma4(o[r], yv.z, vv[2]); fma4(o[r], yv.w, vv[3]);
                }
            }
            #pragma unroll
            for (int r = 0; r < 8; ++r) {
                if (act[r]) {
                    if (slot) {
                        o[r].x += ov[r].x; o[r].y += ov[r].y;
                        o[r].z += ov[r].z; o[r].w += ov[r].w;
                    }
                    *(float4*)(out + (size_t)tok[r] * HD + coff) = o[r];
                }
            }
        }
    }
}

extern "C" void kernel_launch(void* const* d_in, const int* in_sizes, int n_in,
                              void* d_out, int out_size, void* d_ws, size_t ws_size,
                              hipStream_t stream)
{
    const float* h    = (const float*)d_in[0];
    const float* Wr   = (const float*)d_in[1];
    const float* U    = (const float*)d_in[2];
    const float* V    = (const float*)d_in[3];
    const float* attr = (const float*)d_in[4];
    const float* Wa   = (const float*)d_in[5];
    float* outp = (float*)d_out;

    char* ws = (char*)d_ws;
    int*   cnt      = (int*)ws;
    int*   tok_list = (int*)(ws + 256);
    float* cf_list  = (float*)(ws + 256 + (size_t)NLIST * CAPL * 4);
    float* UT       = (float*)(ws + 256 + (size_t)2 * NLIST * CAPL * 4);
    float* sc_g     = UT + (size_t)NS * RDIM * HD;
    float* aw       = sc_g + (size_t)BT * NS;
    float* y_ws     = aw + NS + 28;   // pad to 16B alignment

    hipLaunchKernelGGL(k_prep,   dim3(NS * 8 + 1), dim3(256), 0, stream,
                       U, attr, Wa, cnt, UT, aw);
    hipLaunchKernelGGL(k_router, dim3(BT / 16),    dim3(512), 0, stream, h, Wr, sc_g);
    hipLaunchKernelGGL(k_tail,   dim3(BT / 256),   dim3(256), 0, stream,
                       sc_g, aw, cnt, tok_list, cf_list);
    hipLaunchKernelGGL(k_A,      dim3(NLIST, 14),  dim3(512), 0, stream,
                       h, cnt, tok_list, cf_list, UT, y_ws);
    hipLaunchKernelGGL(k_B,      dim3(NS, 7),      dim3(512), 0, stream,
                       V, cnt, tok_list, y_ws, outp, 0);
    hipLaunchKernelGGL(k_B,      dim3(NS, 7),      dim3(512), 0, stream,
                       V, cnt, tok_list, y_ws, outp, 1);
}

// Round 5
// 264.003 us; speedup vs baseline: 1.3800x; 1.1345x over previous
//
#include <hip/hip_runtime.h>
#include <cstddef>

#define BT    8192
#define HD    2048
#define NS    32
#define RDIM  16
#define AD    32
#define CAPL  448            // per (slot,schema) list cap; lambda=256, sigma~15.7 -> +12 sigma
#define NLIST 64

// ---------------- workspace layout (bytes) ----------------
// 0         int   cnt[64]                         (pad to 1024)
// 1024      int   tok_list[64][448]               114688
// 115712    float cf_list[64][448]                114688
// 230400    float UT[32][16][2048]                4 MB
// 4424704   float aw[32]                          (pad to 256)
// 4424960   union { float sc_part[8][8192][32];   8 MB   (router -> tail)
//                   float y_part[4][64][448][16]; 7 MB } (A -> B; stream-ordered)

__device__ __forceinline__ float dot4(const float4 a, const float4 b) {
    return a.x * b.x + a.y * b.y + a.z * b.z + a.w * b.w;
}
__device__ __forceinline__ void fma4(float4& o, const float a, const float4 b) {
    o.x += a * b.x; o.y += a * b.y; o.z += a * b.z; o.w += a * b.w;
}

// ---------------- prep: zero counters + transpose U + aw = sigmoid(attr@Wa) ----------------
__global__ __launch_bounds__(256) void k_prep(const float* __restrict__ U,
                                              const float* __restrict__ attr,
                                              const float* __restrict__ Wa,
                                              int* __restrict__ cnt,
                                              float* __restrict__ UT,
                                              float* __restrict__ aw) {
    const int bx = blockIdx.x;
    if (bx == NS * 8) {
        if (threadIdx.x < NLIST) cnt[threadIdx.x] = 0;
        if (threadIdx.x >= 64 && threadIdx.x < 64 + NS) {
            const int s = threadIdx.x - 64;
            float sum = 0.f;
            #pragma unroll 1
            for (int d = 0; d < AD; ++d) sum += attr[s * AD + d] * Wa[d];
            aw[s] = 1.f / (1.f + __expf(-sum));
        }
        return;
    }
    const int s = bx >> 3, jc = bx & 7;
    const int j = jc * 256 + threadIdx.x;
    const float4* Up = (const float4*)(U + ((size_t)s * HD + j) * RDIM);
    const float4 a = Up[0], b = Up[1], c = Up[2], d = Up[3];
    float* Tp = UT + (size_t)s * RDIM * HD + j;
    Tp[0]       = a.x; Tp[HD]      = a.y; Tp[2*HD]   = a.z; Tp[3*HD]   = a.w;
    Tp[4*HD]    = b.x; Tp[5*HD]    = b.y; Tp[6*HD]   = b.z; Tp[7*HD]   = b.w;
    Tp[8*HD]    = c.x; Tp[9*HD]    = c.y; Tp[10*HD]  = c.z; Tp[11*HD]  = c.w;
    Tp[12*HD]   = d.x; Tp[13*HD]   = d.y; Tp[14*HD]  = d.z; Tp[15*HD]  = d.w;
}

// ---------------- router: block = (128-token group, 256-dim slice) ----------------
// Stage Wr[32 sch][256 dims] (32 KB) ONCE, one barrier; then 8 waves run FREE
// (no further barriers): per iter, 2 tokens x 32 schemas from LDS, butterfly
// reduce, write partial scores. k_tail sums the 8 slices.
__global__ __launch_bounds__(512) void k_router(
    const float* __restrict__ h, const float* __restrict__ Wr,
    float* __restrict__ sc_part)
{
    __shared__ __align__(16) float wst[NS * 256];     // 32 KB
    const int tid = threadIdx.x, w = tid >> 6, lane = tid & 63;
    const int tg = blockIdx.x, cs = blockIdx.y;
    float4* const wst4 = (float4*)wst;

    #pragma unroll
    for (int j = 0; j < 4; ++j) {
        const int f = tid + j * 512;
        const int s = f >> 6, e = f & 63;
        wst4[f] = *((const float4*)(Wr + (size_t)s * HD + cs * 256) + e);
    }
    __syncthreads();   // the only barrier

    #pragma unroll 1
    for (int it = 0; it < 8; ++it) {
        const int ta = tg * 128 + it * 16 + w * 2;
        const float4 h0 = *(const float4*)(h + (size_t)ta * HD + cs * 256 + lane * 4);
        const float4 h1 = *(const float4*)(h + (size_t)(ta + 1) * HD + cs * 256 + lane * 4);

        float acc[64];
        #pragma unroll
        for (int m = 0; m < 64; ++m) acc[m] = 0.f;
        #pragma unroll
        for (int s = 0; s < 32; ++s) {
            const float4 wv = wst4[s * 64 + lane];
            acc[s]      += dot4(h0, wv);
            acc[32 + s] += dot4(h1, wv);
        }
        // butterfly reduce 64 vals over 64 lanes: lane L ends with m=L (t=L>>5, s=L&31)
        #pragma unroll
        for (int st = 0; st < 6; ++st) {
            const int d = 1 << st;
            const bool up = (lane & d) != 0;
            const int half = 32 >> st;
            #pragma unroll
            for (int i = 0; i < half; ++i) {
                const float lo = acc[2 * i], hi = acc[2 * i + 1];
                const float keep = up ? hi : lo, send = up ? lo : hi;
                acc[i] = keep + __shfl_xor(send, d, 64);
            }
        }
        sc_part[((size_t)cs * BT + ta + (lane >> 5)) * NS + (lane & 31)] = acc[0];
    }
}

// ---------------- tail: thread-per-token sum slices + top-2 / softmax / lists ----------------
__global__ __launch_bounds__(256) void k_tail(
    const float* __restrict__ sc_part, const float* __restrict__ aw,
    int* __restrict__ cnt, int* __restrict__ tok_list, float* __restrict__ cf_list)
{
    const int t = blockIdx.x * 256 + threadIdx.x;
    float s[32];
    #pragma unroll
    for (int k = 0; k < 32; ++k) s[k] = 0.f;
    #pragma unroll 1
    for (int cs = 0; cs < 8; ++cs) {
        const float4* sp = (const float4*)(sc_part + ((size_t)cs * BT + t) * NS);
        #pragma unroll
        for (int j = 0; j < 8; ++j) {
            const float4 v = sp[j];
            s[4*j] += v.x; s[4*j+1] += v.y; s[4*j+2] += v.z; s[4*j+3] += v.w;
        }
    }
    float m1 = -1e30f, m2 = -1e30f;
    int i1 = 0, i2 = 0;
    #pragma unroll
    for (int k = 0; k < 32; ++k) {   // strict > keeps lowest index on ties (lax.top_k)
        const float v = s[k];
        if (v > m1) { m2 = m1; i2 = i1; m1 = v; i1 = k; }
        else if (v > m2) { m2 = v; i2 = k; }
    }
    float Z = 0.f;
    #pragma unroll
    for (int k = 0; k < 32; ++k) Z += __expf(s[k] - m1);
    const float e2  = __expf(m2 - m1);
    // g = softmax(sc)*mask renormed by (sum + 1e-8): G_i = e_i / (e1+e2 + 1e-8*Z)
    const float den = 1.f + e2 + 1e-8f * Z;
    const float G1 = 1.f / den, G2 = e2 / den;
    const float mult = 0.9f + 0.2f * (G1 * aw[i1] + G2 * aw[i2]);
    const float c1 = G1 * mult, c2 = G2 * mult;
    int p = atomicAdd(cnt + i1, 1);
    if (p < CAPL) { tok_list[i1 * CAPL + p] = t; cf_list[i1 * CAPL + p] = c1; }
    p = atomicAdd(cnt + NS + i2, 1);
    if (p < CAPL) { tok_list[(NS + i2) * CAPL + p] = t; cf_list[(NS + i2) * CAPL + p] = c2; }
}

// ---------------- pass A: block = (list g, 512-dim quarter cq) ----------------
// Stage UT[s][16 k][quarter] (32 KB) ONCE, one barrier; waves then free-run over
// the list's tokens (4/wave/iter, no barriers): gather h slice, 64 dot4/k-step,
// butterfly, write partial y (quarter-local sum). k_B sums the 4 quarters.
__global__ __launch_bounds__(512) void k_A(
    const float* __restrict__ h, const int* __restrict__ cnt,
    const int* __restrict__ tok_list, const float* __restrict__ cf_list,
    const float* __restrict__ UT, float* __restrict__ y_part)
{
    __shared__ __align__(16) float ust[RDIM * 512];   // 32 KB
    const int g = blockIdx.x, s = g & (NS - 1), cq = blockIdx.y;
    int count = cnt[g]; if (count > CAPL) count = CAPL;
    const int tid = threadIdx.x, w = tid >> 6, lane = tid & 63;
    const float* UTs = UT + (size_t)s * RDIM * HD;
    float4* const ust4 = (float4*)ust;

    #pragma unroll
    for (int j = 0; j < 4; ++j) {
        const int f = tid + j * 512;
        const int k = f >> 7, e = f & 127;
        ust4[f] = *((const float4*)(UTs + (size_t)k * HD + cq * 512) + e);
    }
    __syncthreads();   // the only barrier

    #pragma unroll 1
    for (int it = 0; it * 32 + w * 4 < count; ++it) {
        const int idx0 = it * 32 + w * 4;
        int tok[4]; float cf[4];
        #pragma unroll
        for (int r = 0; r < 4; ++r) {
            const int idx = idx0 + r;
            const bool vld = idx < count;
            tok[r] = vld ? tok_list[g * CAPL + idx] : 0;
            cf[r]  = vld ? cf_list[g * CAPL + idx] : 0.f;
        }

        float acc[64];
        #pragma unroll
        for (int m = 0; m < 64; ++m) acc[m] = 0.f;

        #pragma unroll
        for (int c2 = 0; c2 < 2; ++c2) {
            float4 hv[4];
            #pragma unroll
            for (int r = 0; r < 4; ++r)
                hv[r] = *(const float4*)(h + (size_t)tok[r] * HD + cq * 512 + c2 * 256 + lane * 4);
            #pragma unroll
            for (int k = 0; k < 16; ++k) {
                const float4 uv = ust4[k * 128 + c2 * 64 + lane];
                #pragma unroll
                for (int r = 0; r < 4; ++r)
                    acc[r * 16 + k] += dot4(hv[r], uv);
            }
        }

        // butterfly reduce: lane L ends holding value m=L (r = L>>4, k = L&15)
        #pragma unroll
        for (int st = 0; st < 6; ++st) {
            const int d = 1 << st;
            const bool up = (lane & d) != 0;
            const int half = 32 >> st;
            #pragma unroll
            for (int i = 0; i < half; ++i) {
                const float lo = acc[2 * i], hi = acc[2 * i + 1];
                const float keep = up ? hi : lo, send = up ? lo : hi;
                acc[i] = keep + __shfl_xor(send, d, 64);
            }
        }
        const int rr = lane >> 4;
        const float cfv = rr == 0 ? cf[0] : rr == 1 ? cf[1] : rr == 2 ? cf[2] : cf[3];
        y_part[((size_t)(cq * NLIST + g) * CAPL + idx0) * 16 + lane] = acc[0] * cfv;
    }
}

// ---------------- pass B: block = (schema, 256-dim slice cs) ----------------
// Stage V[s][16 k][slice] (16 KB) ONCE, one barrier; waves free-run over tokens
// (4/wave/iter): load+sum the 4 y quarters (coalesced), broadcast via wave-private
// LDS, 64 fma4, store out slice. slot 0 stores, slot 1 RMW (separate launch).
__global__ __launch_bounds__(512) void k_B(
    const float* __restrict__ V, const int* __restrict__ cnt,
    const int* __restrict__ tok_list, const float* __restrict__ y_part,
    float* __restrict__ out, const int slot)
{
    __shared__ __align__(16) float vst[RDIM * 256];   // 16 KB
    __shared__ __align__(16) float yld[8 * 64];       // 2 KB, wave-private regions
    const int sch = blockIdx.x, cs = blockIdx.y;
    const int g = slot * NS + sch;
    int count = cnt[g]; if (count > CAPL) count = CAPL;
    const int tid = threadIdx.x, w = tid >> 6, lane = tid & 63;
    const float* Vs = V + (size_t)sch * RDIM * HD;
    float4* const vst4 = (float4*)vst;
    float4* const yld4 = (float4*)yld;

    #pragma unroll
    for (int j = 0; j < 2; ++j) {
        const int f = tid + j * 512;
        const int k = f >> 6, e = f & 63;
        vst4[f] = *((const float4*)(Vs + (size_t)k * HD + cs * 256) + e);
    }
    __syncthreads();   // the only barrier

    #pragma unroll 1
    for (int it = 0; it * 32 + w * 4 < count; ++it) {
        const int idx0 = it * 32 + w * 4;
        int tok[4]; bool act[4];
        #pragma unroll
        for (int r = 0; r < 4; ++r) {
            const int idx = idx0 + r;
            act[r] = idx < count;
            tok[r] = act[r] ? tok_list[g * CAPL + idx] : 0;
        }

        // lane L: token r=L>>4, k=L&15; sum the 4 dim-quarter partials
        float ysum = 0.f;
        #pragma unroll
        for (int q = 0; q < 4; ++q)
            ysum += y_part[((size_t)(q * NLIST + g) * CAPL + idx0) * 16 + lane];
        yld[w * 64 + lane] = ysum;   // wave-private: no barrier needed

        float4 ov[4];
        if (slot) {
            #pragma unroll
            for (int r = 0; r < 4; ++r)
                if (act[r]) ov[r] = *(const float4*)(out + (size_t)tok[r] * HD + cs * 256 + lane * 4);
        }
        float4 o[4];
        #pragma unroll
        for (int r = 0; r < 4; ++r) o[r] = make_float4(0.f, 0.f, 0.f, 0.f);

        #pragma unroll
        for (int kg = 0; kg < 4; ++kg) {
            float4 vv[4];
            #pragma unroll
            for (int q = 0; q < 4; ++q)
                vv[q] = vst4[(kg * 4 + q) * 64 + lane];
            #pragma unroll
            for (int r = 0; r < 4; ++r) {
                const float4 yv = yld4[w * 16 + r * 4 + kg];   // broadcast read
                fma4(o[r], yv.x, vv[0]); fma4(o[r], yv.y, vv[1]);
                fma4(o[r], yv.z, vv[2]); fma4(o[r], yv.w, vv[3]);
            }
        }
        #pragma unroll
        for (int r = 0; r < 4; ++r) {
            if (act[r]) {
                if (slot) {
                    o[r].x += ov[r].x; o[r].y += ov[r].y;
                    o[r].z += ov[r].z; o[r].w += ov[r].w;
                }
                *(float4*)(out + (size_t)tok[r] * HD + cs * 256 + lane * 4) = o[r];
            }
        }
    }
}

extern "C" void kernel_launch(void* const* d_in, const int* in_sizes, int n_in,
                              void* d_out, int out_size, void* d_ws, size_t ws_size,
                              hipStream_t stream)
{
    const float* h    = (const float*)d_in[0];
    const float* Wr   = (const float*)d_in[1];
    const float* U    = (const float*)d_in[2];
    const float* V    = (const float*)d_in[3];
    const float* attr = (const float*)d_in[4];
    const float* Wa   = (const float*)d_in[5];
    float* outp = (float*)d_out;

    char* ws = (char*)d_ws;
    int*   cnt      = (int*)ws;
    int*   tok_list = (int*)(ws + 1024);
    float* cf_list  = (float*)(ws + 1024 + (size_t)NLIST * CAPL * 4);
    float* UT       = (float*)(ws + 1024 + (size_t)2 * NLIST * CAPL * 4);
    float* aw       = UT + (size_t)NS * RDIM * HD;
    float* big      = aw + 64;                       // sc_part / y_part union
    float* sc_part  = big;
    float* y_part   = big;

    hipLaunchKernelGGL(k_prep,   dim3(NS * 8 + 1), dim3(256), 0, stream,
                       U, attr, Wa, cnt, UT, aw);
    hipLaunchKernelGGL(k_router, dim3(64, 8),      dim3(512), 0, stream, h, Wr, sc_part);
    hipLaunchKernelGGL(k_tail,   dim3(BT / 256),   dim3(256), 0, stream,
                       sc_part, aw, cnt, tok_list, cf_list);
    hipLaunchKernelGGL(k_A,      dim3(NLIST, 4),   dim3(512), 0, stream,
                       h, cnt, tok_list, cf_list, UT, y_part);
    hipLaunchKernelGGL(k_B,      dim3(NS, 8),      dim3(512), 0, stream,
                       V, cnt, tok_list, y_part, outp, 0);
    hipLaunchKernelGGL(k_B,      dim3(NS, 8),      dim3(512), 0, stream,
                       V, cnt, tok_list, y_part, outp, 1);
}